// Round 1
// baseline (3996.676 us; speedup 1.0000x reference)
//
#include <hip/hip_runtime.h>
#include <math.h>

// Problem constants
#define NROWS 65536      // 32*2048
#define DDIM  768
#define KCODES 1024
#define NCB   8          // code blocks (KCODES / BK)
#define BM    128        // rows per block
#define BK    128        // codes per block
#define DC    16         // D-chunk staged in LDS
#define GAP_TAU 0.0625f  // fp32 score gap below which we re-check in fp64

// ---- output offsets (d_out is float32, outputs concatenated in return order)
#define OUT_LOSS ((size_t)NROWS * DDIM)
#define OUT_IDX  (OUT_LOSS + 1)
#define OUT_MIND (OUT_IDX + NROWS)
#define OUT_PERP (OUT_MIND + NROWS)

// ---- workspace offsets (bytes); total needed ~6.8 MB
#define WS_SUM    0                              // double sum_sqerr
#define WS_NSUS   8                              // int n_suspect
#define WS_NVAL   12                             // unsigned n_valid
#define WS_COUNTS 256                            // float[KCODES]
#define WS_WSQ    (WS_COUNTS + 4*KCODES)         // float[KCODES]
#define WS_ROWS   (WS_WSQ + 4*KCODES)            // float[NROWS] row min score (dist - xsq)
#define WS_ROWI   (WS_ROWS + 4*NROWS)            // int[NROWS] row argmin
#define WS_SUSP   (WS_ROWI + 4*NROWS)            // int[NROWS] suspect rows
#define WS_PM1    (WS_SUSP + 4*NROWS)            // float[NROWS*NCB] partial min
#define WS_PM2    (WS_PM1 + (size_t)4*NROWS*NCB) // float[NROWS*NCB] partial 2nd min
#define WS_PIDX   (WS_PM2 + (size_t)4*NROWS*NCB) // int[NROWS*NCB] partial argmin
#define WS_END    (WS_PIDX + (size_t)4*NROWS*NCB)

template <typename T>
__device__ inline T waveRedAdd(T v) {
#pragma unroll
    for (int o = 32; o; o >>= 1) v += __shfl_xor(v, o);
    return v;
}

// ---------------------------------------------------------------- init
__global__ void k_init(float* counts, int* n_suspect, unsigned* n_valid, double* sum_sqerr) {
    const int t = threadIdx.x;
    if (t == 0) { *n_suspect = 0; *n_valid = 0u; *sum_sqerr = 0.0; }
    for (int k = t; k < KCODES; k += 256) counts[k] = 0.f;
}

// ---------------------------------------------------------------- ||e_k||^2
__global__ __launch_bounds__(256) void k_wsq(const float* __restrict__ W, float* __restrict__ wsq) {
    const int k = blockIdx.x;
    const int t = threadIdx.x;
    const float* w = W + (size_t)k * DDIM;
    const float a = w[t], b = w[t + 256], c = w[t + 512];
    float s = a * a + b * b + c * c;
    s = waveRedAdd(s);
    __shared__ float p[4];
    if ((t & 63) == 0) p[t >> 6] = s;
    __syncthreads();
    if (t == 0) wsq[k] = (p[0] + p[1]) + (p[2] + p[3]);
}

// ---------------------------------------------------------------- main GEMM + per-tile argmin
// score s_k = ||e_k||^2 - 2 x.e_k  (xsq added later; doesn't affect argmin)
// Block: 128 rows x 128 codes, D staged in LDS chunks of 16.
// Per-thread 8x8 register tile; wave lane layout 8x8 (ly=rows, lx=codes) so
// LDS reads are 8-way broadcast + 2-way bank alias (free, m136).
__global__ __launch_bounds__(256, 4) void k_partials(
    const float* __restrict__ A, const float* __restrict__ W,
    const float* __restrict__ wsq,
    float* __restrict__ pm1, float* __restrict__ pm2, int* __restrict__ pidx)
{
    __shared__ __align__(16) float sm[2 * DC * BM];   // Al[16][128] | Wl[16][128]
    float* Al = sm;
    float* Wl = sm + DC * BM;

    const int rb = blockIdx.x, cb = blockIdx.y;
    const int tid = threadIdx.x;
    const int wid = tid >> 6, lane = tid & 63;
    const int lx = lane & 7, ly = lane >> 3;
    const int tx = ((wid & 1) << 3) | lx;   // 0..15 code-tile coord
    const int ty = ((wid >> 1) << 3) | ly;  // 0..15 row-tile coord

    const float* Ab = A + (size_t)rb * BM * DDIM;
    const float* Wb = W + (size_t)cb * BK * DDIM;

    const int sr = tid >> 2;         // 0..63 (row within staging)
    const int sd = (tid & 3) << 2;   // 0,4,8,12 (d within chunk)

    float acc[8][8];
#pragma unroll
    for (int r = 0; r < 8; ++r)
#pragma unroll
        for (int c = 0; c < 8; ++c) acc[r][c] = 0.f;

    // prefetch chunk 0
    float4 pa0 = *(const float4*)(Ab + (size_t)sr * DDIM + sd);
    float4 pa1 = *(const float4*)(Ab + (size_t)(sr + 64) * DDIM + sd);
    float4 pw0 = *(const float4*)(Wb + (size_t)sr * DDIM + sd);
    float4 pw1 = *(const float4*)(Wb + (size_t)(sr + 64) * DDIM + sd);

#pragma unroll 1
    for (int ch = 0; ch < DDIM / DC; ++ch) {
        __syncthreads();   // previous compute done reading LDS
        // store transposed: Al[d][row]
        Al[(sd + 0) * BM + sr] = pa0.x; Al[(sd + 1) * BM + sr] = pa0.y;
        Al[(sd + 2) * BM + sr] = pa0.z; Al[(sd + 3) * BM + sr] = pa0.w;
        Al[(sd + 0) * BM + sr + 64] = pa1.x; Al[(sd + 1) * BM + sr + 64] = pa1.y;
        Al[(sd + 2) * BM + sr + 64] = pa1.z; Al[(sd + 3) * BM + sr + 64] = pa1.w;
        Wl[(sd + 0) * BK + sr] = pw0.x; Wl[(sd + 1) * BK + sr] = pw0.y;
        Wl[(sd + 2) * BK + sr] = pw0.z; Wl[(sd + 3) * BK + sr] = pw0.w;
        Wl[(sd + 0) * BK + sr + 64] = pw1.x; Wl[(sd + 1) * BK + sr + 64] = pw1.y;
        Wl[(sd + 2) * BK + sr + 64] = pw1.z; Wl[(sd + 3) * BK + sr + 64] = pw1.w;
        __syncthreads();
        if (ch + 1 < DDIM / DC) {   // prefetch next chunk; latency hides under compute
            const int d0 = (ch + 1) * DC;
            pa0 = *(const float4*)(Ab + (size_t)sr * DDIM + d0 + sd);
            pa1 = *(const float4*)(Ab + (size_t)(sr + 64) * DDIM + d0 + sd);
            pw0 = *(const float4*)(Wb + (size_t)sr * DDIM + d0 + sd);
            pw1 = *(const float4*)(Wb + (size_t)(sr + 64) * DDIM + d0 + sd);
        }
#pragma unroll
        for (int d = 0; d < DC; ++d) {
            const float4 a0 = *(const float4*)(Al + d * BM + ty * 8);
            const float4 a1 = *(const float4*)(Al + d * BM + ty * 8 + 4);
            const float4 w0 = *(const float4*)(Wl + d * BK + tx * 8);
            const float4 w1 = *(const float4*)(Wl + d * BK + tx * 8 + 4);
            const float av[8] = {a0.x, a0.y, a0.z, a0.w, a1.x, a1.y, a1.z, a1.w};
            const float wv[8] = {w0.x, w0.y, w0.z, w0.w, w1.x, w1.y, w1.z, w1.w};
#pragma unroll
            for (int r = 0; r < 8; ++r)
#pragma unroll
                for (int c = 0; c < 8; ++c)
                    acc[r][c] = fmaf(av[r], wv[c], acc[r][c]);
        }
    }

    // ---------------- epilogue: per-row (min, 2nd-min, argmin) over this code tile
    float wsqv[8];
#pragma unroll
    for (int c = 0; c < 8; ++c) wsqv[c] = wsq[cb * BK + tx * 8 + c];

    __syncthreads();   // done with staging reads; reuse LDS
    float* tm1 = sm;                 // [128][2]
    float* tm2 = sm + 256;
    int*   ti1 = (int*)(sm + 512);

#pragma unroll
    for (int r = 0; r < 8; ++r) {
        float m1 = INFINITY, m2 = INFINITY; int i1 = 0x7fffffff;
#pragma unroll
        for (int c = 0; c < 8; ++c) {
            const float s = fmaf(-2.f, acc[r][c], wsqv[c]);
            const int k = cb * BK + tx * 8 + c;
            if (s < m1) { m2 = m1; m1 = s; i1 = k; }
            else if (s < m2) m2 = s;
        }
        // merge across lx (8 code-columns of this wave)
#pragma unroll
        for (int msk = 1; msk <= 4; msk <<= 1) {
            const float om1 = __shfl_xor(m1, msk);
            const float om2 = __shfl_xor(m2, msk);
            const int   oi1 = __shfl_xor(i1, msk);
            if (om1 < m1 || (om1 == m1 && oi1 < i1)) { m2 = fminf(m1, om2); m1 = om1; i1 = oi1; }
            else m2 = fminf(m2, om1);
        }
        if (lx == 0) {
            const int slot = (ty * 8 + r) * 2 + (wid & 1);
            tm1[slot] = m1; tm2[slot] = m2; ti1[slot] = i1;
        }
    }
    __syncthreads();
    if (tid < BM) {
        float m1 = tm1[tid * 2], m2 = tm2[tid * 2]; int i1 = ti1[tid * 2];
        const float bm1 = tm1[tid * 2 + 1], bm2 = tm2[tid * 2 + 1]; const int bi = ti1[tid * 2 + 1];
        if (bm1 < m1 || (bm1 == m1 && bi < i1)) { m2 = fminf(m1, bm2); m1 = bm1; i1 = bi; }
        else m2 = fminf(m2, bm1);
        const size_t row = (size_t)rb * BM + tid;
        pm1[row * NCB + cb] = m1;
        pm2[row * NCB + cb] = m2;
        pidx[row * NCB + cb] = i1;
    }
}

// ---------------------------------------------------------------- merge 8 partials per row
__global__ __launch_bounds__(256) void k_merge(
    const float* __restrict__ pm1, const float* __restrict__ pm2, const int* __restrict__ pidx,
    float* __restrict__ row_s, int* __restrict__ row_idx,
    int* __restrict__ suspects, int* __restrict__ n_suspect)
{
    const int row = blockIdx.x * 256 + threadIdx.x;
    float m1 = INFINITY, m2 = INFINITY; int i1 = 0x7fffffff;
#pragma unroll
    for (int cb = 0; cb < NCB; ++cb) {
        const float bm1 = pm1[(size_t)row * NCB + cb];
        const float bm2 = pm2[(size_t)row * NCB + cb];
        const int   bi  = pidx[(size_t)row * NCB + cb];
        if (bm1 < m1 || (bm1 == m1 && bi < i1)) { m2 = fminf(m1, bm2); m1 = bm1; i1 = bi; }
        else m2 = fminf(m2, bm1);
    }
    row_s[row] = m1;
    row_idx[row] = i1;
    if (m2 - m1 < GAP_TAU) {   // near-tie: fp32 argmin may differ from true argmin
        const int p = atomicAdd(n_suspect, 1);
        suspects[p] = row;
    }
}

// ---------------------------------------------------------------- fp64 re-check of near-ties
// One block per suspect row (grid-strided). Wave w scans codes [w*256,(w+1)*256).
__global__ __launch_bounds__(256) void k_repair(
    const float* __restrict__ A, const float* __restrict__ W,
    const int* __restrict__ suspects, const int* __restrict__ n_suspect,
    float* __restrict__ row_s, int* __restrict__ row_idx)
{
    __shared__ float xrow[DDIM];
    __shared__ double wb[4]; __shared__ int wbi[4];
    __shared__ double sxsq;
    const int ns = *n_suspect;
    const int wid = threadIdx.x >> 6, lane = threadIdx.x & 63;
    for (int s = blockIdx.x; s < ns; s += gridDim.x) {
        const int row = suspects[s];
        __syncthreads();
        for (int i = threadIdx.x; i < DDIM; i += 256) xrow[i] = A[(size_t)row * DDIM + i];
        __syncthreads();
        if (wid == 0) {
            double xs = 0.0;
            for (int i = lane; i < DDIM; i += 64) { const double t = xrow[i]; xs += t * t; }
            xs = waveRedAdd(xs);
            if (lane == 0) sxsq = xs;
        }
        double best = 1e300; int bi = 0;
        const int k0 = wid * (KCODES / 4);
        for (int kk = 0; kk < KCODES / 4; ++kk) {
            const int k = k0 + kk;
            const float* wr = W + (size_t)k * DDIM;
            double d = 0.0;
            for (int i = lane; i < DDIM; i += 64) {
                const double t = (double)xrow[i] - (double)wr[i];
                d = fma(t, t, d);
            }
            d = waveRedAdd(d);
            if (d < best) { best = d; bi = k; }   // ascending k => first-index tiebreak
        }
        if (lane == 0) { wb[wid] = best; wbi[wid] = bi; }
        __syncthreads();
        if (threadIdx.x == 0) {
            double b = wb[0]; int i1 = wbi[0];
#pragma unroll
            for (int w = 1; w < 4; ++w) if (wb[w] < b) { b = wb[w]; i1 = wbi[w]; }
            row_idx[row] = i1;
            row_s[row] = (float)(b - sxsq);   // store score form (dist - xsq)
        }
    }
}

// ---------------------------------------------------------------- quantize + losses + idx/min_d outputs
__global__ __launch_bounds__(256) void k_quantize(
    const float* __restrict__ A, const float* __restrict__ W,
    const float* __restrict__ row_s, const int* __restrict__ row_idx,
    float* __restrict__ out, float* __restrict__ counts,
    unsigned int* __restrict__ n_valid, double* __restrict__ sum_sqerr)
{
    const int wid = threadIdx.x >> 6, lane = threadIdx.x & 63;
    const int row = blockIdx.x * 4 + wid;
    const float* x = A + (size_t)row * DDIM;
    float4 xv[3];
#pragma unroll
    for (int j = 0; j < 3; ++j) xv[j] = *(const float4*)(x + (lane + 64 * j) * 4);
    float xsq = 0.f;
#pragma unroll
    for (int j = 0; j < 3; ++j)
        xsq += xv[j].x * xv[j].x + xv[j].y * xv[j].y + xv[j].z * xv[j].z + xv[j].w * xv[j].w;
    xsq = waveRedAdd(xsq);
    const bool valid = xsq > 1e-12f;            // norm > 1e-6
    const float maskf = valid ? 1.f : 0.f;
    const int idx = row_idx[row];
    const int idxm = valid ? idx : 0;
    const float* w = W + (size_t)idx * DDIM;
    float* oq = out + (size_t)row * DDIM;
    float e2 = 0.f;
#pragma unroll
    for (int j = 0; j < 3; ++j) {
        const float4 wv = *(const float4*)(w + (lane + 64 * j) * 4);
        const float xs[4] = {xv[j].x, xv[j].y, xv[j].z, xv[j].w};
        const float ws[4] = {wv.x, wv.y, wv.z, wv.w};
        float os[4];
#pragma unroll
        for (int c = 0; c < 4; ++c) {
            const float q = ws[c] * maskf;          // q_flat = weight[idx] * mask
            os[c] = xs[c] + (q - xs[c]);            // quantized_st, fp32 op order as ref
            const float d = xs[c] - q;
            e2 += d * d;
        }
        float4 ov; ov.x = os[0]; ov.y = os[1]; ov.z = os[2]; ov.w = os[3];
        *(float4*)(oq + (lane + 64 * j) * 4) = ov;
    }
    e2 = waveRedAdd(e2);
    if (lane == 0) {
        atomicAdd(sum_sqerr, (double)(maskf * e2));
        if (valid) {
            atomicAdd(n_valid, 1u);
            atomicAdd(&counts[idxm], 1.0f);
        }
        out[OUT_IDX + row]  = (float)idxm;
        out[OUT_MIND + row] = valid ? (xsq + row_s[row]) : 0.f;
    }
}

// ---------------------------------------------------------------- scalar losses
__global__ __launch_bounds__(256) void k_final(
    const float* __restrict__ counts, const unsigned int* __restrict__ n_valid,
    const double* __restrict__ sum_sqerr, float* __restrict__ out)
{
    const int t = threadIdx.x;
    const float nv = (float)(*n_valid);
    double ent = 0.0;
    for (int k = t; k < KCODES; k += 256) {
        const float p = counts[k] / nv;
        ent += (double)(p * logf(p + 1e-10f));
    }
    ent = waveRedAdd(ent);
    __shared__ double ps[4];
    if ((t & 63) == 0) ps[t >> 6] = ent;
    __syncthreads();
    if (t == 0) {
        const double e = ps[0] + ps[1] + ps[2] + ps[3];
        const double perp = exp(-e);
        const double ploss = -log(perp + 1e-10);
        const double commit = *sum_sqerr / ((double)(*n_valid) * (double)DDIM);
        out[OUT_LOSS] = (float)(0.25 * commit + 0.1 * ploss);
        out[OUT_PERP] = (float)perp;
    }
}

// ----------------------------------------------------------------
extern "C" void kernel_launch(void* const* d_in, const int* in_sizes, int n_in,
                              void* d_out, int out_size, void* d_ws, size_t ws_size,
                              hipStream_t stream) {
    const float* A = (const float*)d_in[0];   // [65536, 768]
    const float* W = (const float*)d_in[1];   // [1024, 768]
    float* out = (float*)d_out;
    char* ws = (char*)d_ws;
    if (ws_size < (size_t)WS_END) return;     // needs ~6.8 MB scratch

    double*   sum_sqerr = (double*)(ws + WS_SUM);
    int*      n_suspect = (int*)(ws + WS_NSUS);
    unsigned* n_valid   = (unsigned*)(ws + WS_NVAL);
    float*    counts    = (float*)(ws + WS_COUNTS);
    float*    wsq       = (float*)(ws + WS_WSQ);
    float*    row_s     = (float*)(ws + WS_ROWS);
    int*      row_idx   = (int*)(ws + WS_ROWI);
    int*      suspects  = (int*)(ws + WS_SUSP);
    float*    pm1       = (float*)(ws + WS_PM1);
    float*    pm2       = (float*)(ws + WS_PM2);
    int*      pidx      = (int*)(ws + WS_PIDX);

    hipLaunchKernelGGL(k_init, dim3(1), dim3(256), 0, stream, counts, n_suspect, n_valid, sum_sqerr);
    hipLaunchKernelGGL(k_wsq, dim3(KCODES), dim3(256), 0, stream, W, wsq);
    hipLaunchKernelGGL(k_partials, dim3(NROWS / BM, NCB), dim3(256), 0, stream, A, W, wsq, pm1, pm2, pidx);
    hipLaunchKernelGGL(k_merge, dim3(NROWS / 256), dim3(256), 0, stream, pm1, pm2, pidx, row_s, row_idx, suspects, n_suspect);
    hipLaunchKernelGGL(k_repair, dim3(256), dim3(256), 0, stream, A, W, suspects, n_suspect, row_s, row_idx);
    hipLaunchKernelGGL(k_quantize, dim3(NROWS / 4), dim3(256), 0, stream, A, W, row_s, row_idx, out, counts, n_valid, sum_sqerr);
    hipLaunchKernelGGL(k_final, dim3(1), dim3(256), 0, stream, counts, n_valid, sum_sqerr, out);
}